// Round 10
// baseline (143.412 us; speedup 1.0000x reference)
//
#include <hip/hip_runtime.h>
#include <hip/hip_bf16.h>

typedef __attribute__((ext_vector_type(4))) float  f32x4;
typedef __attribute__((ext_vector_type(8))) _Float16 f16x8;

// ---- weight pre-transform: w1 -> Bt1[64 n][32 k] f16; w2 -> Bt2[9 tap][128 c2][64 c1] f16
__global__ void transform_kernel(const float* __restrict__ w1, const float* __restrict__ w2,
                                 _Float16* __restrict__ Bt1, _Float16* __restrict__ Bt2)
{
    const int i = blockIdx.x * 256 + threadIdx.x;
    if (i < 64 * 32) {
        const int n = i >> 5, k = i & 31;
        const float v = (k < 27) ? w1[n * 27 + k] : 0.0f;
        Bt1[i] = (_Float16)v;
    }
    const int j = i - 64 * 32;
    if (j >= 0 && j < 9 * 128 * 64) {
        const int tap = j / (128 * 64);
        const int rem = j % (128 * 64);
        const int n = rem >> 6;          // c2
        const int c1 = rem & 63;
        Bt2[j] = (_Float16)w2[((size_t)n * 64 + c1) * 9 + tap];
    }
}

// ---- fused gather + conv1 + conv2. Block = (mc: 2 out-rows, img). 256 thr, 4 waves.
// LDS: patch 5.5K + im2col 25.6K + slab(5 h1-rows) 40K = 70.4 KB -> 2 blocks/CU.
// conv2: wave tile 32x64 (2x2 wave grid), A from LDS slab, B reg-prefetched from Bt2.
__global__ __launch_bounds__(256, 2) void fused_kernel(
    const float* __restrict__ x, const float* __restrict__ l,
    const _Float16* __restrict__ Bt1, const float* __restrict__ b1,
    const _Float16* __restrict__ Bt2, const float* __restrict__ b2,
    float* __restrict__ out)
{
    const int bk = blockIdx.y;               // 0..191
    const int mc = blockIdx.x;               // 0..15 : out-rows 2mc..2mc+1
    const int b  = bk / 3, ksc = bk % 3;
    const int step = 1 << ksc;
    const int half = 32 << ksc;
    const int y0 = mc * 4;                   // first h1 row of the 5-row slab

    const int t = threadIdx.x, wave = t >> 6, lane = t & 63;
    const int lrow = lane & 15, kb = lane >> 4;
    const int wq = wave >> 1, wn = wave & 1; // 2x2 wave grid: M-half / N-half

    __shared__ float    patch[3 * 7 * 66];  // 5544 B unique gather window
    __shared__ _Float16 A1[320 * 40];       // 25600 B im2col (5 rows)
    __shared__ _Float16 slab[320 * 64];     // 40960 B h1 slab (5 rows)

    const float ly = l[b * 2 + 0], lx = l[b * 2 + 1];
    int cy = (int)floorf(0.5f * (ly + 1.0f) * 512.0f);
    int cx = (int)floorf(0.5f * (lx + 1.0f) * 512.0f);
    cy = min(max(cy, 0), 512);
    cx = min(max(cx, 0), 512);
    const int sy = cy - half, sx = cx - half;

    // ---- phase 0: gather 7x66 patch (h1 rows y0-1 .. y0+5), 3 channels
    const float* xb = x + (size_t)b * 3 * 262144;
    for (int i = t; i < 3 * 7 * 66; i += 256) {
        const int c = i / 462, r = i % 462;
        const int ry = r / 66, xx = r % 66;
        const int yy = y0 - 1 + ry, col = xx - 1;
        const int iy = sy + yy * step, ix = sx + col * step;
        float v = 0.0f;
        if (yy >= 0 && yy < 64 && col >= 0 && col < 64 &&
            iy >= 0 && iy < 512 && ix >= 0 && ix < 512)
            v = xb[(size_t)c * 262144 + iy * 512 + ix];
        patch[i] = v;
    }

    // per-lane weight/bias registers
    f16x8 w1f[4];
    float b1v[4], b2v[4];
    #pragma unroll
    for (int nf = 0; nf < 4; ++nf) {
        w1f[nf] = *(const f16x8*)(Bt1 + ((size_t)(nf * 16 + lrow)) * 32 + kb * 8);
        b1v[nf] = b1[nf * 16 + lrow];
        b2v[nf] = b2[wn * 64 + nf * 16 + lrow];
    }
    __syncthreads();

    // ---- phase 1a: im2col for all 5 rows (320 px)
    for (int i = t; i < 320; i += 256) {
        const int pyl = i >> 6, px = i & 63;
        _Float16* arow = &A1[i * 40];
        #pragma unroll
        for (int k = 0; k < 27; ++k) {
            const int c = k / 9, rr = k % 9, kh = rr / 3, kw = rr % 3;
            arow[k] = (_Float16)patch[c * 462 + (pyl + kh) * 66 + (px + kw)];
        }
        #pragma unroll
        for (int k = 27; k < 32; ++k) arow[k] = (_Float16)0.0f;
    }
    __syncthreads();

    // ---- phase 1b: conv1 MFMA, 20 m-frags over 4 waves (5 each)
    {
        f32x4 acc1[5][4];
        #pragma unroll
        for (int mf = 0; mf < 5; ++mf)
            #pragma unroll
            for (int nf = 0; nf < 4; ++nf)
                #pragma unroll
                for (int r = 0; r < 4; ++r) acc1[mf][nf][r] = 0.0f;

        #pragma unroll
        for (int mf = 0; mf < 5; ++mf) {
            const f16x8 afr = *(const f16x8*)&A1[((wave * 5 + mf) * 16 + lrow) * 40 + kb * 8];
            #pragma unroll
            for (int nf = 0; nf < 4; ++nf)
                acc1[mf][nf] = __builtin_amdgcn_mfma_f32_16x16x32_f16(afr, w1f[nf], acc1[mf][nf], 0, 0, 0);
        }

        // epilogue: bias+ReLU -> slab (parity-split + bank-swizzle)
        #pragma unroll
        for (int mf = 0; mf < 5; ++mf) {
            #pragma unroll
            for (int nf = 0; nf < 4; ++nf) {
                const int c1 = nf * 16 + lrow;
                #pragma unroll
                for (int r = 0; r < 4; ++r) {
                    const int pp = (wave * 5 + mf) * 16 + kb * 4 + r;
                    const int rowl = pp >> 6, xcol = pp & 63;
                    float v = fmaxf(acc1[mf][nf][r] + b1v[nf], 0.0f);
                    if (mc == 15 && rowl == 4) v = 0.0f;      // y=64 pad row
                    const int psx = ((xcol & 1) << 5) | (xcol >> 1);
                    const int c1s = c1 ^ ((psx & 7) << 3);
                    slab[(rowl * 64 + psx) * 64 + c1s] = (_Float16)v;
                }
            }
        }
    }
    __syncthreads();

    // ---- phase 2: conv2, 9 taps, barrier-free. B prefetched to regs (static dbuf).
    f32x4 acc2[2][4];
    #pragma unroll
    for (int mf = 0; mf < 2; ++mf)
        #pragma unroll
        for (int nf = 0; nf < 4; ++nf)
            #pragma unroll
            for (int r = 0; r < 4; ++r) acc2[mf][nf][r] = 0.0f;

#define BLOAD(dst, tapi)                                                          \
    _Pragma("unroll")                                                             \
    for (int c1h = 0; c1h < 2; ++c1h)                                             \
        _Pragma("unroll")                                                         \
        for (int nf = 0; nf < 4; ++nf)                                            \
            dst[c1h * 4 + nf] = *(const f16x8*)(Bt2 + (size_t)(tapi) * 8192 +     \
                (wn * 64 + nf * 16 + lrow) * 64 + c1h * 32 + kb * 8);

#define TAPSTEP(tapi, BC)                                                         \
    {                                                                             \
        constexpr int kh_ = (tapi) / 3, kw_ = (tapi) % 3, par_ = kw_ & 1;         \
        _Pragma("unroll")                                                         \
        for (int c1h = 0; c1h < 2; ++c1h) {                                       \
            const int jt = c1h * 4 + kb;                                          \
            f16x8 afr[2];                                                         \
            _Pragma("unroll")                                                     \
            for (int mf = 0; mf < 2; ++mf) {                                      \
                const int ml  = wq * 32 + mf * 16 + lrow;                         \
                const int oyl = ml >> 5, ox = ml & 31;                            \
                const int p   = (2 * oyl + kh_) * 64 + par_ * 32 + (ox + (kw_ >> 1)); \
                f16x8 v = *(const f16x8*)&slab[p * 64 + (jt ^ (p & 7)) * 8];      \
                if (kw_ == 2 && ox == 31) v = (f16x8){};                          \
                afr[mf] = v;                                                      \
            }                                                                     \
            _Pragma("unroll")                                                     \
            for (int nf = 0; nf < 4; ++nf)                                        \
                _Pragma("unroll")                                                 \
                for (int mf = 0; mf < 2; ++mf)                                    \
                    acc2[mf][nf] = __builtin_amdgcn_mfma_f32_16x16x32_f16(        \
                        afr[mf], BC[c1h * 4 + nf], acc2[mf][nf], 0, 0, 0);        \
        }                                                                         \
    }

    f16x8 bA[8], bB[8];
    BLOAD(bA, 0)
    BLOAD(bB, 1)  TAPSTEP(0, bA)
    BLOAD(bA, 2)  TAPSTEP(1, bB)
    BLOAD(bB, 3)  TAPSTEP(2, bA)
    BLOAD(bA, 4)  TAPSTEP(3, bB)
    BLOAD(bB, 5)  TAPSTEP(4, bA)
    BLOAD(bA, 6)  TAPSTEP(5, bB)
    BLOAD(bB, 7)  TAPSTEP(6, bA)
    BLOAD(bA, 8)  TAPSTEP(7, bB)
                  TAPSTEP(8, bA)

    // ---- out: [bk][128][32][32]
    float* ob = out + (size_t)bk * 131072;
    #pragma unroll
    for (int mf = 0; mf < 2; ++mf) {
        const int m0 = mc * 64 + wq * 32 + mf * 16 + kb * 4;
        #pragma unroll
        for (int nf = 0; nf < 4; ++nf) {
            const int c2 = wn * 64 + nf * 16 + lrow;
            f32x4 v;
            #pragma unroll
            for (int r = 0; r < 4; ++r) v[r] = fmaxf(acc2[mf][nf][r] + b2v[nf], 0.0f);
            *(f32x4*)(ob + (size_t)c2 * 1024 + m0) = v;
        }
    }
}

extern "C" void kernel_launch(void* const* d_in, const int* in_sizes, int n_in,
                              void* d_out, int out_size, void* d_ws, size_t ws_size,
                              hipStream_t stream) {
    const float* x  = (const float*)d_in[0];
    const float* l  = (const float*)d_in[1];
    const float* w1 = (const float*)d_in[2];
    const float* b1 = (const float*)d_in[3];
    const float* w2 = (const float*)d_in[4];
    const float* b2 = (const float*)d_in[5];
    float* out = (float*)d_out;

    _Float16* Bt1 = (_Float16*)d_ws;         // 2048 f16
    _Float16* Bt2 = Bt1 + 64 * 32;           // 73728 f16

    transform_kernel<<<296, 256, 0, stream>>>(w1, w2, Bt1, Bt2);
    fused_kernel<<<dim3(16, 192), 256, 0, stream>>>(x, l, Bt1, b1, Bt2, b2, out);
}

// Round 11
// 121.582 us; speedup vs baseline: 1.1796x; 1.1796x over previous
//
#include <hip/hip_runtime.h>
#include <hip/hip_bf16.h>

typedef __attribute__((ext_vector_type(4))) float  f32x4;
typedef __attribute__((ext_vector_type(8))) _Float16 f16x8;

#define LDA1 40   // conv1 A_lds row stride in fp16 elems

static __device__ __forceinline__ void gld_lds16(const void* g, void* l) {
    __builtin_amdgcn_global_load_lds(
        (const __attribute__((address_space(1))) void*)g,
        (__attribute__((address_space(3))) void*)l, 16, 0, 0);
}

// ---- weight pre-transform: w1 -> Bt1[64 n][32 k] f16; w2 -> Bt2[9 tap][128 c2][64 c1] f16
__global__ void transform_kernel(const float* __restrict__ w1, const float* __restrict__ w2,
                                 _Float16* __restrict__ Bt1, _Float16* __restrict__ Bt2)
{
    const int i = blockIdx.x * 256 + threadIdx.x;
    if (i < 64 * 32) {
        const int n = i >> 5, k = i & 31;
        const float v = (k < 27) ? w1[n * 27 + k] : 0.0f;
        Bt1[i] = (_Float16)v;
    }
    const int j = i - 64 * 32;
    if (j >= 0 && j < 9 * 128 * 64) {
        const int tap = j / (128 * 64);
        const int rem = j % (128 * 64);
        const int n = rem >> 6;          // c2
        const int c1 = rem & 63;
        Bt2[j] = (_Float16)w2[((size_t)n * 64 + c1) * 9 + tap];
    }
}

// ---- conv1 (gather + 3x3 s1 SAME + ReLU) as MFMA (r8 version, known-good).
// h1 channels-last, parity-split p = y*64+(x&1)*32+(x>>1), c1 XOR-swizzled.
__global__ __launch_bounds__(256) void conv1_mfma(
    const float* __restrict__ x, const float* __restrict__ l,
    const _Float16* __restrict__ Bt1, const float* __restrict__ b1,
    _Float16* __restrict__ h1, int bk0)
{
    const int img = blockIdx.y;
    const int bk  = bk0 + img;
    const int b   = bk / 3, ksc = bk % 3;
    const int step = 1 << ksc;
    const int half = 32 << ksc;
    const int py0 = blockIdx.x * 4;

    const float ly = l[b * 2 + 0], lx = l[b * 2 + 1];
    int cy = (int)floorf(0.5f * (ly + 1.0f) * 512.0f);
    int cx = (int)floorf(0.5f * (lx + 1.0f) * 512.0f);
    cy = min(max(cy, 0), 512);
    cx = min(max(cx, 0), 512);
    const int sy = cy - half, sx = cx - half;

    __shared__ float    patch[3 * 6 * 66];
    __shared__ _Float16 A_lds[256 * LDA1];
    __shared__ _Float16 out_t[256 * 64];

    const int t = threadIdx.x;
    const float* xb = x + (size_t)b * 3 * 262144;
    for (int i = t; i < 3 * 6 * 66; i += 256) {
        const int c  = i / 396, r = i % 396;
        const int ry = r / 66, xx = r % 66;
        const int yy = py0 - 1 + ry;
        const int col = xx - 1;
        const int iy = sy + yy * step, ix = sx + col * step;
        float v = 0.0f;
        if (yy >= 0 && yy < 64 && col >= 0 && col < 64 &&
            iy >= 0 && iy < 512 && ix >= 0 && ix < 512)
            v = xb[(size_t)c * 262144 + iy * 512 + ix];
        patch[i] = v;
    }
    __syncthreads();

    {
        const int pyl = t >> 6, px = t & 63;
        _Float16* arow = &A_lds[t * LDA1];
        #pragma unroll
        for (int k = 0; k < 27; ++k) {
            const int c = k / 9, rr = k % 9, kh = rr / 3, kw = rr % 3;
            arow[k] = (_Float16)patch[c * 396 + (pyl + kh) * 66 + (px + kw)];
        }
        #pragma unroll
        for (int k = 27; k < 32; ++k) arow[k] = (_Float16)0.0f;
    }
    __syncthreads();

    const int wave = t >> 6, lane = t & 63;
    const int lrow = lane & 15, kb = lane >> 4;

    f16x8 bfr[4];
    #pragma unroll
    for (int nf = 0; nf < 4; ++nf)
        bfr[nf] = *(const f16x8*)(Bt1 + ((size_t)(nf * 16 + lrow)) * 32 + kb * 8);

    f32x4 acc[4][4];
    #pragma unroll
    for (int mf = 0; mf < 4; ++mf)
        #pragma unroll
        for (int nf = 0; nf < 4; ++nf)
            #pragma unroll
            for (int r = 0; r < 4; ++r) acc[mf][nf][r] = 0.0f;

    #pragma unroll
    for (int mf = 0; mf < 4; ++mf) {
        const f16x8 afr = *(const f16x8*)(&A_lds[((wave * 4 + mf) * 16 + lrow) * LDA1 + kb * 8]);
        #pragma unroll
        for (int nf = 0; nf < 4; ++nf)
            acc[mf][nf] = __builtin_amdgcn_mfma_f32_16x16x32_f16(afr, bfr[nf], acc[mf][nf], 0, 0, 0);
    }

    #pragma unroll
    for (int mf = 0; mf < 4; ++mf) {
        const int ml0 = (wave * 4 + mf) * 16 + kb * 4;
        #pragma unroll
        for (int nf = 0; nf < 4; ++nf) {
            const int c1 = nf * 16 + lrow;
            const float bb = b1[c1];
            #pragma unroll
            for (int r = 0; r < 4; ++r) {
                const float v = fmaxf(acc[mf][nf][r] + bb, 0.0f);
                const int ml = ml0 + r;
                const int xcol = ml & 63;
                const int psx = ((xcol & 1) << 5) | (xcol >> 1);
                const int pl  = (ml & ~63) | psx;
                const int c1s = c1 ^ ((psx & 7) << 3);
                out_t[pl * 64 + c1s] = (_Float16)v;
            }
        }
    }
    __syncthreads();

    _Float16* hb = h1 + (size_t)img * 4096 * 64 + (size_t)py0 * 64 * 64;
    #pragma unroll
    for (int j = 0; j < 8; ++j) {
        const int idx = j * 256 + t;
        *(f16x8*)(hb + (size_t)idx * 8) = *(const f16x8*)&out_t[idx * 8];
    }
}

// ---- conv2: barrier-free LDS-A / register-B implicit GEMM.
// Block = (img, mc: 4 out-rows = 128 px) x N=128. Waves 2x2 -> wave tile 64x64.
// A: 9-row h1 slab (72KB) staged once via global_load_lds -> 2 blocks/CU.
// B: register double-buffer prefetched from L2-resident Bt2. One barrier total.
__global__ __launch_bounds__(256, 2) void conv2_mfma(
    const _Float16* __restrict__ h1, const _Float16* __restrict__ Bt2,
    const float* __restrict__ b2, float* __restrict__ out, int bk0)
{
    const int img = blockIdx.y;
    const int bk  = bk0 + img;
    const int mc  = blockIdx.x;               // 0..7 : out rows 4mc..4mc+3
    const int t = threadIdx.x, wave = t >> 6, lane = t & 63;
    const int lrow = lane & 15, kb = lane >> 4;
    const int wq = wave >> 1, wn = wave & 1;  // 2x2 wave grid

    __shared__ _Float16 As[9 * 4096];         // 73728 B

    const _Float16* hb = h1 + (size_t)img * 4096 * 64;
    const int ys = mc * 8;                    // first h1 row of slab
    const int nrows = (mc == 7) ? 8 : 9;

    if (mc == 7) {                            // zero pad_high row (y=64)
        f16x8 z = {};
        *(f16x8*)&As[8 * 4096 + t * 16]     = z;
        *(f16x8*)&As[8 * 4096 + t * 16 + 8] = z;
    }
    {   // stage slab: nrows*512 16B chunks
        const _Float16* ga = hb + (size_t)ys * 4096;
        #pragma unroll
        for (int j = 0; j < 18; ++j) {
            if (j < nrows * 2) {
                const int c = j * 256 + t;
                gld_lds16(ga + (size_t)c * 8, As + (j * 256 + wave * 64) * 8);
            }
        }
    }

    float b2v[4];
    #pragma unroll
    for (int nf = 0; nf < 4; ++nf) b2v[nf] = b2[wn * 64 + nf * 16 + lrow];

    f32x4 acc2[4][4];
    #pragma unroll
    for (int mf = 0; mf < 4; ++mf)
        #pragma unroll
        for (int nf = 0; nf < 4; ++nf)
            #pragma unroll
            for (int r = 0; r < 4; ++r) acc2[mf][nf][r] = 0.0f;

    __syncthreads();                          // slab ready (drains vmcnt)

#define BLOAD(dst, tapi)                                                          \
    _Pragma("unroll")                                                             \
    for (int c1h = 0; c1h < 2; ++c1h)                                             \
        _Pragma("unroll")                                                         \
        for (int nf = 0; nf < 4; ++nf)                                            \
            dst[c1h * 4 + nf] = *(const f16x8*)(Bt2 + (size_t)(tapi) * 8192 +     \
                (wn * 64 + nf * 16 + lrow) * 64 + c1h * 32 + kb * 8);

#define TAPSTEP(tapi, BC)                                                         \
    {                                                                             \
        constexpr int kh_ = (tapi) / 3, kw_ = (tapi) % 3, par_ = kw_ & 1;         \
        _Pragma("unroll")                                                         \
        for (int c1h = 0; c1h < 2; ++c1h) {                                       \
            const int jt = c1h * 4 + kb;                                          \
            f16x8 afr[4];                                                         \
            _Pragma("unroll")                                                     \
            for (int mf = 0; mf < 4; ++mf) {                                      \
                const int ml  = wq * 64 + mf * 16 + lrow;                         \
                const int oyl = ml >> 5, ox = ml & 31;                            \
                const int p   = (2 * oyl + kh_) * 64 + par_ * 32 + (ox + (kw_ >> 1)); \
                f16x8 v = *(const f16x8*)&As[p * 64 + (jt ^ (p & 7)) * 8];        \
                if (kw_ == 2 && ox == 31) v = (f16x8){};                          \
                afr[mf] = v;                                                      \
            }                                                                     \
            _Pragma("unroll")                                                     \
            for (int nf = 0; nf < 4; ++nf)                                        \
                _Pragma("unroll")                                                 \
                for (int mf = 0; mf < 4; ++mf)                                    \
                    acc2[mf][nf] = __builtin_amdgcn_mfma_f32_16x16x32_f16(        \
                        afr[mf], BC[c1h * 4 + nf], acc2[mf][nf], 0, 0, 0);        \
        }                                                                         \
    }

    f16x8 bA[8], bB[8];
    BLOAD(bA, 0)
    BLOAD(bB, 1)  TAPSTEP(0, bA)
    BLOAD(bA, 2)  TAPSTEP(1, bB)
    BLOAD(bB, 3)  TAPSTEP(2, bA)
    BLOAD(bA, 4)  TAPSTEP(3, bB)
    BLOAD(bB, 5)  TAPSTEP(4, bA)
    BLOAD(bA, 6)  TAPSTEP(5, bB)
    BLOAD(bB, 7)  TAPSTEP(6, bA)
    BLOAD(bA, 8)  TAPSTEP(7, bB)
                  TAPSTEP(8, bA)

    float* ob = out + (size_t)bk * 131072;
    #pragma unroll
    for (int mf = 0; mf < 4; ++mf) {
        const int m0 = mc * 128 + wq * 64 + mf * 16 + kb * 4;
        #pragma unroll
        for (int nf = 0; nf < 4; ++nf) {
            const int c2 = wn * 64 + nf * 16 + lrow;
            f32x4 v;
            #pragma unroll
            for (int r = 0; r < 4; ++r) v[r] = fmaxf(acc2[mf][nf][r] + b2v[nf], 0.0f);
            *(f32x4*)(ob + (size_t)c2 * 1024 + m0) = v;
        }
    }
}

extern "C" void kernel_launch(void* const* d_in, const int* in_sizes, int n_in,
                              void* d_out, int out_size, void* d_ws, size_t ws_size,
                              hipStream_t stream) {
    const float* x  = (const float*)d_in[0];
    const float* l  = (const float*)d_in[1];
    const float* w1 = (const float*)d_in[2];
    const float* b1 = (const float*)d_in[3];
    const float* w2 = (const float*)d_in[4];
    const float* b2 = (const float*)d_in[5];
    float* out = (float*)d_out;

    _Float16* Bt1 = (_Float16*)d_ws;                                   // 2048  f16
    _Float16* Bt2 = Bt1 + 64 * 32;                                     // 73728 f16
    _Float16* h1  = (_Float16*)((char*)d_ws + 160 * 1024);             // chunked

    const int total_imgs = 192;                                        // B*K
    const size_t per_img = (size_t)4096 * 64 * sizeof(_Float16);       // 512 KB
    size_t h1_cap = (ws_size > 160 * 1024) ? ws_size - 160 * 1024 : 0;
    int ipc = (int)(h1_cap / per_img);
    if (ipc > total_imgs) ipc = total_imgs;
    if (ipc < 1) ipc = 1;

    transform_kernel<<<296, 256, 0, stream>>>(w1, w2, Bt1, Bt2);

    for (int bk0 = 0; bk0 < total_imgs; bk0 += ipc) {
        const int n = (total_imgs - bk0 < ipc) ? (total_imgs - bk0) : ipc;
        conv1_mfma<<<dim3(16, n), 256, 0, stream>>>(x, l, Bt1, b1, h1, bk0);
        conv2_mfma<<<dim3(8, n), 256, 0, stream>>>(h1, Bt2, b2, out, bk0);
    }
}

// Round 12
// 107.181 us; speedup vs baseline: 1.3380x; 1.1344x over previous
//
#include <hip/hip_runtime.h>
#include <hip/hip_bf16.h>

typedef __attribute__((ext_vector_type(4))) float  f32x4;
typedef __attribute__((ext_vector_type(8))) _Float16 f16x8;

#define LDA1 40   // conv1 A_lds row stride in fp16 elems

static __device__ __forceinline__ void gld_lds16(const void* g, void* l) {
    __builtin_amdgcn_global_load_lds(
        (const __attribute__((address_space(1))) void*)g,
        (__attribute__((address_space(3))) void*)l, 16, 0, 0);
}

// ---- weight pre-transform: w1 -> Bt1[64 n][32 k] f16; w2 -> Bt2[9 tap][128 c2][64 c1] f16
__global__ void transform_kernel(const float* __restrict__ w1, const float* __restrict__ w2,
                                 _Float16* __restrict__ Bt1, _Float16* __restrict__ Bt2)
{
    const int i = blockIdx.x * 256 + threadIdx.x;
    if (i < 64 * 32) {
        const int n = i >> 5, k = i & 31;
        const float v = (k < 27) ? w1[n * 27 + k] : 0.0f;
        Bt1[i] = (_Float16)v;
    }
    const int j = i - 64 * 32;
    if (j >= 0 && j < 9 * 128 * 64) {
        const int tap = j / (128 * 64);
        const int rem = j % (128 * 64);
        const int n = rem >> 6;          // c2
        const int c1 = rem & 63;
        Bt2[j] = (_Float16)w2[((size_t)n * 64 + c1) * 9 + tap];
    }
}

// ---- conv1 (r8 version, unchanged, known-good).
// h1 channels-last, parity-split p = y*64+(x&1)*32+(x>>1), c1 XOR-swizzled.
__global__ __launch_bounds__(256) void conv1_mfma(
    const float* __restrict__ x, const float* __restrict__ l,
    const _Float16* __restrict__ Bt1, const float* __restrict__ b1,
    _Float16* __restrict__ h1, int bk0)
{
    const int img = blockIdx.y;
    const int bk  = bk0 + img;
    const int b   = bk / 3, ksc = bk % 3;
    const int step = 1 << ksc;
    const int half = 32 << ksc;
    const int py0 = blockIdx.x * 4;

    const float ly = l[b * 2 + 0], lx = l[b * 2 + 1];
    int cy = (int)floorf(0.5f * (ly + 1.0f) * 512.0f);
    int cx = (int)floorf(0.5f * (lx + 1.0f) * 512.0f);
    cy = min(max(cy, 0), 512);
    cx = min(max(cx, 0), 512);
    const int sy = cy - half, sx = cx - half;

    __shared__ float    patch[3 * 6 * 66];
    __shared__ _Float16 A_lds[256 * LDA1];
    __shared__ _Float16 out_t[256 * 64];

    const int t = threadIdx.x;
    const float* xb = x + (size_t)b * 3 * 262144;
    for (int i = t; i < 3 * 6 * 66; i += 256) {
        const int c  = i / 396, r = i % 396;
        const int ry = r / 66, xx = r % 66;
        const int yy = py0 - 1 + ry;
        const int col = xx - 1;
        const int iy = sy + yy * step, ix = sx + col * step;
        float v = 0.0f;
        if (yy >= 0 && yy < 64 && col >= 0 && col < 64 &&
            iy >= 0 && iy < 512 && ix >= 0 && ix < 512)
            v = xb[(size_t)c * 262144 + iy * 512 + ix];
        patch[i] = v;
    }
    __syncthreads();

    {
        const int pyl = t >> 6, px = t & 63;
        _Float16* arow = &A_lds[t * LDA1];
        #pragma unroll
        for (int k = 0; k < 27; ++k) {
            const int c = k / 9, rr = k % 9, kh = rr / 3, kw = rr % 3;
            arow[k] = (_Float16)patch[c * 396 + (pyl + kh) * 66 + (px + kw)];
        }
        #pragma unroll
        for (int k = 27; k < 32; ++k) arow[k] = (_Float16)0.0f;
    }
    __syncthreads();

    const int wave = t >> 6, lane = t & 63;
    const int lrow = lane & 15, kb = lane >> 4;

    f16x8 bfr[4];
    #pragma unroll
    for (int nf = 0; nf < 4; ++nf)
        bfr[nf] = *(const f16x8*)(Bt1 + ((size_t)(nf * 16 + lrow)) * 32 + kb * 8);

    f32x4 acc[4][4];
    #pragma unroll
    for (int mf = 0; mf < 4; ++mf)
        #pragma unroll
        for (int nf = 0; nf < 4; ++nf)
            #pragma unroll
            for (int r = 0; r < 4; ++r) acc[mf][nf][r] = 0.0f;

    #pragma unroll
    for (int mf = 0; mf < 4; ++mf) {
        const f16x8 afr = *(const f16x8*)(&A_lds[((wave * 4 + mf) * 16 + lrow) * LDA1 + kb * 8]);
        #pragma unroll
        for (int nf = 0; nf < 4; ++nf)
            acc[mf][nf] = __builtin_amdgcn_mfma_f32_16x16x32_f16(afr, bfr[nf], acc[mf][nf], 0, 0, 0);
    }

    #pragma unroll
    for (int mf = 0; mf < 4; ++mf) {
        const int ml0 = (wave * 4 + mf) * 16 + kb * 4;
        #pragma unroll
        for (int nf = 0; nf < 4; ++nf) {
            const int c1 = nf * 16 + lrow;
            const float bb = b1[c1];
            #pragma unroll
            for (int r = 0; r < 4; ++r) {
                const float v = fmaxf(acc[mf][nf][r] + bb, 0.0f);
                const int ml = ml0 + r;
                const int xcol = ml & 63;
                const int psx = ((xcol & 1) << 5) | (xcol >> 1);
                const int pl  = (ml & ~63) | psx;
                const int c1s = c1 ^ ((psx & 7) << 3);
                out_t[pl * 64 + c1s] = (_Float16)v;
            }
        }
    }
    __syncthreads();

    _Float16* hb = h1 + (size_t)img * 4096 * 64 + (size_t)py0 * 64 * 64;
    #pragma unroll
    for (int j = 0; j < 8; ++j) {
        const int idx = j * 256 + t;
        *(f16x8*)(hb + (size_t)idx * 8) = *(const f16x8*)&out_t[idx * 8];
    }
}

// ---- conv2: A-slab-only LDS (40KB -> 4 blocks/CU), barrier-free tap chain.
// Block = (img, mc: 2 out-rows = 64 px) x N=128. Each wave: full M=64, N=32 slice.
// Per tap/thread: 8 ds_read_b128 (A) + 4 reg B-loads + 16 MFMA. T5 setprio on MFMAs.
__global__ __launch_bounds__(256, 4) void conv2_mfma(
    const _Float16* __restrict__ h1, const _Float16* __restrict__ Bt2,
    const float* __restrict__ b2, float* __restrict__ out, int bk0)
{
    const int img = blockIdx.y;
    const int bk  = bk0 + img;
    const int mc  = blockIdx.x;               // 0..15 : out rows 2mc..2mc+1
    const int t = threadIdx.x, wave = t >> 6, lane = t & 63;
    const int lrow = lane & 15, kb = lane >> 4;

    __shared__ _Float16 As[5 * 4096];         // 40960 B

    const _Float16* hb = h1 + (size_t)img * 4096 * 64;
    const int ys = mc * 4;                    // first h1 row of slab
    const int nrows = (mc == 15) ? 4 : 5;

    if (mc == 15) {                           // zero pad_high row (y=64)
        f16x8 z = {};
        *(f16x8*)&As[4 * 4096 + t * 16]     = z;
        *(f16x8*)&As[4 * 4096 + t * 16 + 8] = z;
    }
    {   // stage slab once via global_load_lds
        const _Float16* ga = hb + (size_t)ys * 4096;
        #pragma unroll
        for (int j = 0; j < 10; ++j) {
            if (j < nrows * 2) {
                const int c = j * 256 + t;
                gld_lds16(ga + (size_t)c * 8, As + (j * 256 + wave * 64) * 8);
            }
        }
    }

    float b2v[2];
    #pragma unroll
    for (int nf = 0; nf < 2; ++nf) b2v[nf] = b2[wave * 32 + nf * 16 + lrow];

    f32x4 acc2[4][2];                          // [mf][nf]
    #pragma unroll
    for (int mf = 0; mf < 4; ++mf)
        #pragma unroll
        for (int nf = 0; nf < 2; ++nf)
            #pragma unroll
            for (int r = 0; r < 4; ++r) acc2[mf][nf][r] = 0.0f;

    __syncthreads();                           // slab ready (drains vmcnt)

#define BLOAD(dst, tapi)                                                          \
    _Pragma("unroll")                                                             \
    for (int c1h = 0; c1h < 2; ++c1h)                                             \
        _Pragma("unroll")                                                         \
        for (int nf = 0; nf < 2; ++nf)                                            \
            dst[c1h * 2 + nf] = *(const f16x8*)(Bt2 + (size_t)(tapi) * 8192 +     \
                (wave * 32 + nf * 16 + lrow) * 64 + c1h * 32 + kb * 8);

#define TAPSTEP(tapi, BC)                                                         \
    {                                                                             \
        constexpr int kh_ = (tapi) / 3, kw_ = (tapi) % 3, par_ = kw_ & 1;         \
        _Pragma("unroll")                                                         \
        for (int c1h = 0; c1h < 2; ++c1h) {                                       \
            const int jt = c1h * 4 + kb;                                          \
            f16x8 afr[4];                                                         \
            _Pragma("unroll")                                                     \
            for (int mf = 0; mf < 4; ++mf) {                                      \
                const int ml  = mf * 16 + lrow;                                   \
                const int oyl = ml >> 5, ox = ml & 31;                            \
                const int p   = (2 * oyl + kh_) * 64 + par_ * 32 + (ox + (kw_ >> 1)); \
                f16x8 v = *(const f16x8*)&As[p * 64 + (jt ^ (p & 7)) * 8];        \
                if (kw_ == 2 && ox == 31) v = (f16x8){};                          \
                afr[mf] = v;                                                      \
            }                                                                     \
            __builtin_amdgcn_s_setprio(1);                                        \
            _Pragma("unroll")                                                     \
            for (int nf = 0; nf < 2; ++nf)                                        \
                _Pragma("unroll")                                                 \
                for (int mf = 0; mf < 4; ++mf)                                    \
                    acc2[mf][nf] = __builtin_amdgcn_mfma_f32_16x16x32_f16(        \
                        afr[mf], BC[c1h * 2 + nf], acc2[mf][nf], 0, 0, 0);        \
            __builtin_amdgcn_s_setprio(0);                                        \
        }                                                                         \
    }

    f16x8 bA[4], bB[4];
    BLOAD(bA, 0)
    BLOAD(bB, 1)  TAPSTEP(0, bA)
    BLOAD(bA, 2)  TAPSTEP(1, bB)
    BLOAD(bB, 3)  TAPSTEP(2, bA)
    BLOAD(bA, 4)  TAPSTEP(3, bB)
    BLOAD(bB, 5)  TAPSTEP(4, bA)
    BLOAD(bA, 6)  TAPSTEP(5, bB)
    BLOAD(bB, 7)  TAPSTEP(6, bA)
    BLOAD(bA, 8)  TAPSTEP(7, bB)
                  TAPSTEP(8, bA)

    float* ob = out + (size_t)bk * 131072;
    #pragma unroll
    for (int mf = 0; mf < 4; ++mf) {
        const int m0 = mc * 64 + mf * 16 + kb * 4;
        #pragma unroll
        for (int nf = 0; nf < 2; ++nf) {
            const int c2 = wave * 32 + nf * 16 + lrow;
            f32x4 v;
            #pragma unroll
            for (int r = 0; r < 4; ++r) v[r] = fmaxf(acc2[mf][nf][r] + b2v[nf], 0.0f);
            *(f32x4*)(ob + (size_t)c2 * 1024 + m0) = v;
        }
    }
}

extern "C" void kernel_launch(void* const* d_in, const int* in_sizes, int n_in,
                              void* d_out, int out_size, void* d_ws, size_t ws_size,
                              hipStream_t stream) {
    const float* x  = (const float*)d_in[0];
    const float* l  = (const float*)d_in[1];
    const float* w1 = (const float*)d_in[2];
    const float* b1 = (const float*)d_in[3];
    const float* w2 = (const float*)d_in[4];
    const float* b2 = (const float*)d_in[5];
    float* out = (float*)d_out;

    _Float16* Bt1 = (_Float16*)d_ws;                                   // 2048  f16
    _Float16* Bt2 = Bt1 + 64 * 32;                                     // 73728 f16
    _Float16* h1  = (_Float16*)((char*)d_ws + 160 * 1024);             // chunked

    const int total_imgs = 192;                                        // B*K
    const size_t per_img = (size_t)4096 * 64 * sizeof(_Float16);       // 512 KB
    size_t h1_cap = (ws_size > 160 * 1024) ? ws_size - 160 * 1024 : 0;
    int ipc = (int)(h1_cap / per_img);
    if (ipc > total_imgs) ipc = total_imgs;
    if (ipc < 1) ipc = 1;

    transform_kernel<<<296, 256, 0, stream>>>(w1, w2, Bt1, Bt2);

    for (int bk0 = 0; bk0 < total_imgs; bk0 += ipc) {
        const int n = (total_imgs - bk0 < ipc) ? (total_imgs - bk0) : ipc;
        conv1_mfma<<<dim3(16, n), 256, 0, stream>>>(x, l, Bt1, b1, h1, bk0);
        conv2_mfma<<<dim3(16, n), 256, 0, stream>>>(h1, Bt2, b2, out, bk0);
    }
}